// Round 13
// baseline (248.856 us; speedup 1.0000x reference)
//
#include <hip/hip_runtime.h>
#include <hip/hip_fp16.h>
#include <math.h>

#define N_NODES 50000
#define N_EDGES 800000
#define ET (N_EDGES + N_NODES)   // edges + self loops
#define IN_DIM 128
#define H1DIM 64                 // HEADS*HID
#define HEADS 8
#define HID 8
#define OUT_DIM 64
#define NEG_SLOPE 0.2f

#define SCAN_TILE 256
#define NTILES ((N_NODES + SCAN_TILE - 1) / SCAN_TILE)   // 196
#define RC 8                      // cached score iterations per lane (4 slots -> deg <= 32)
#define PF 6                      // prefetched feature-row iterations (deg <= 24)

#define LIN1_WAVES (N_NODES / 8)                 // 6250
#define LIN1_BLOCKS ((LIN1_WAVES + 3) / 4)       // 1563
#define EB ((ET + 255) / 256)                    // 3321 (count blocks, placed FIRST)

__device__ __forceinline__ float lrelu(float v) { return v >= 0.f ? v : NEG_SLOPE * v; }

__device__ __forceinline__ float rdlane(float v, int l) {
    return __int_as_float(__builtin_amdgcn_readlane(__float_as_int(v), l));
}

// unpack 8 fp16 (raw uint4) and FMA into a[8]
__device__ __forceinline__ void fma8raw(uint4 u, float alpha, float* a) {
    float2 f0 = __half22float2(*(const __half2*)&u.x);
    float2 f1 = __half22float2(*(const __half2*)&u.y);
    float2 f2 = __half22float2(*(const __half2*)&u.z);
    float2 f3 = __half22float2(*(const __half2*)&u.w);
    a[0] += f0.x * alpha; a[1] += f0.y * alpha;
    a[2] += f1.x * alpha; a[3] += f1.y * alpha;
    a[4] += f2.x * alpha; a[5] += f2.y * alpha;
    a[6] += f3.x * alpha; a[7] += f3.y * alpha;
}

__device__ __forceinline__ void fma8h(const __half* __restrict__ base, float alpha, float* a) {
    fma8raw(*reinterpret_cast<const uint4*>(base), alpha, a);
}

// edge_index is int32 on device (validated round 4)
__device__ __forceinline__ void edge_nodes(const int* __restrict__ ei, int e, int& s, int& d) {
    if (e < N_EDGES) { s = ei[e]; d = ei[N_EDGES + e]; }
    else             { s = e - N_EDGES; d = s; }
}

// ---------------- fused: count-with-pos (blocks [0,EB)) + lin1 (rest) ----------------
// 8-way privatized counters: c = blockIdx&7 aligns with round-robin XCD dispatch,
// so each cnt8 sub-array's lines stay in one XCD's L2 (no cross-XCD ping-pong).

__global__ __launch_bounds__(256) void cl1_kernel(
    const int* __restrict__ ei, int* __restrict__ cnt8, int* __restrict__ pos,
    const float* __restrict__ x, const float* __restrict__ W1,
    const float* __restrict__ a_src, const float* __restrict__ a_dst,
    __half* __restrict__ h1, float* __restrict__ ssrc, float* __restrict__ sdst)
{
    if (blockIdx.x < EB) {
        int i = blockIdx.x * 256 + threadIdx.x;
        if (i >= ET) return;
        int s, d; edge_nodes(ei, i, s, d);
        pos[i] = atomicAdd(&cnt8[(blockIdx.x & 7) * N_NODES + d], 1);
        return;
    }
    int wid = threadIdx.x >> 6, t = threadIdx.x & 63;
    int g = (blockIdx.x - EB) * 4 + wid;
    if (g >= LIN1_WAVES) return;
    int n0 = g * 8;

    float x0[8], x1[8];
    #pragma unroll
    for (int nn = 0; nn < 8; ++nn) {
        x0[nn] = x[(n0 + nn) * IN_DIM + t];
        x1[nn] = x[(n0 + nn) * IN_DIM + 64 + t];
    }
    float acc[8] = {0,0,0,0,0,0,0,0};
    #pragma unroll 8
    for (int k = 0; k < 64; ++k) {
        float w = W1[k * 64 + t];
        #pragma unroll
        for (int nn = 0; nn < 8; ++nn) acc[nn] += rdlane(x0[nn], k) * w;
    }
    #pragma unroll 8
    for (int k = 0; k < 64; ++k) {
        float w = W1[(k + 64) * 64 + t];
        #pragma unroll
        for (int nn = 0; nn < 8; ++nn) acc[nn] += rdlane(x1[nn], k) * w;
    }

    float av = a_src[t], bv = a_dst[t];
    #pragma unroll
    for (int nn = 0; nn < 8; ++nn) {
        int n = n0 + nn;
        h1[n * 64 + t] = __float2half(acc[nn]);
        float rs = acc[nn] * av, rd = acc[nn] * bv;
        rs += __shfl_xor(rs, 1); rs += __shfl_xor(rs, 2); rs += __shfl_xor(rs, 4);
        rd += __shfl_xor(rd, 1); rd += __shfl_xor(rd, 2); rd += __shfl_xor(rd, 4);
        if ((t & 7) == 0) { ssrc[n * 8 + (t >> 3)] = rs; sdst[n * 8 + (t >> 3)] = rd; }
    }
}

// ---------------- scans ----------------

__global__ __launch_bounds__(SCAN_TILE) void scanA_kernel(
    const int* __restrict__ cnt8, int* __restrict__ row, int* __restrict__ aux)
{
    __shared__ int sh[SCAN_TILE];
    int t = threadIdx.x, i = blockIdx.x * SCAN_TILE + t;
    int v = 0;
    if (i < N_NODES) {
        #pragma unroll
        for (int c = 0; c < 8; ++c) v += cnt8[c * N_NODES + i];
    }
    sh[t] = v;
    __syncthreads();
    #pragma unroll
    for (int off = 1; off < SCAN_TILE; off <<= 1) {
        int add = (t >= off) ? sh[t - off] : 0;
        __syncthreads();
        sh[t] += add;
        __syncthreads();
    }
    if (i < N_NODES) row[i] = sh[t] - v;
    if (t == SCAN_TILE - 1) aux[blockIdx.x] = sh[t];
}

__global__ __launch_bounds__(SCAN_TILE) void scanB_kernel(int* __restrict__ aux, int* __restrict__ row) {
    __shared__ int sh[SCAN_TILE];
    int t = threadIdx.x;
    int v = (t < NTILES) ? aux[t] : 0;
    sh[t] = v;
    __syncthreads();
    #pragma unroll
    for (int off = 1; off < SCAN_TILE; off <<= 1) {
        int add = (t >= off) ? sh[t - off] : 0;
        __syncthreads();
        sh[t] += add;
        __syncthreads();
    }
    if (t < NTILES) aux[t] = sh[t] - v;
    if (t == NTILES - 1) row[N_NODES] = sh[t];
}

// finalize row and emit per-privatization-slot base offsets
__global__ __launch_bounds__(SCAN_TILE) void scanC_kernel(
    const int* __restrict__ aux, int* __restrict__ row,
    const int* __restrict__ cnt8, int* __restrict__ off8)
{
    int i = blockIdx.x * SCAN_TILE + threadIdx.x;
    if (i >= N_NODES) return;
    int r = row[i] + aux[i >> 8];
    row[i] = r;
    int run = r;
    #pragma unroll
    for (int c = 0; c < 8; ++c) {
        off8[c * N_NODES + i] = run;
        run += cnt8[c * N_NODES + i];
    }
}

// atomic-free fill: c recomputed from edge id (count blocks were 256-wide)
__global__ void fill_kernel(const int* __restrict__ ei, const int* __restrict__ off8,
                            const int* __restrict__ pos, int* __restrict__ adj)
{
    int i = blockIdx.x * blockDim.x + threadIdx.x;
    if (i >= ET) return;
    int s, d; edge_nodes(ei, i, s, d);
    int c = (i >> 8) & 7;
    adj[off8[c * N_NODES + d] + pos[i]] = s;
}

// ---------------- layer-1 node kernel: 2 nodes per wave ----------------
// lane t: half = t>>5 (node select), tt = t&31, slot = tt>>3 (4 slots), h = tt&7

__global__ __launch_bounds__(256) void l1_kernel(
    const int* __restrict__ row, const int* __restrict__ adj,
    const __half* __restrict__ h1, const float* __restrict__ s1, const float* __restrict__ t1,
    const float* __restrict__ b1, const float* __restrict__ W2,
    const float* __restrict__ as2, const float* __restrict__ ad2,
    __half* __restrict__ h2, float* __restrict__ s2, float* __restrict__ t2)
{
    int wid = threadIdx.x >> 6, t = threadIdx.x & 63;
    int half = t >> 5, tt = t & 31;
    int n = blockIdx.x * 8 + wid * 2 + half;
    int beg = row[n], end = row[n + 1];
    int slot = tt >> 3, h = tt & 7;
    float sd = t1[n * 8 + h];
    const int e0 = beg + slot;
    const int hb = half << 5;                     // half base lane

    // pass 1: gather scores + prefetch first PF feature rows
    int   sv[RC];
    float p[RC];
    uint4 raw[PF];
    float m = -3e38f;
    #pragma unroll
    for (int it = 0; it < RC; ++it) {
        int e = e0 + it * 4;
        bool ok = e < end;
        int s = ok ? adj[e] : n;
        sv[it] = s;
        float v = ok ? lrelu(s1[s * 8 + h] + sd) : -3e38f;
        p[it] = v;
        m = fmaxf(m, v);
        if (it < PF) raw[it] = *reinterpret_cast<const uint4*>(h1 + (size_t)s * 64 + h * 8);
    }
    for (int e = e0 + RC * 4; e < end; e += 4)    // improbable tail (deg > 32)
        m = fmaxf(m, lrelu(s1[adj[e] * 8 + h] + sd));
    m = fmaxf(m, __shfl_xor(m, 8));
    m = fmaxf(m, __shfl_xor(m, 16));

    float den = 0.f;
    #pragma unroll
    for (int it = 0; it < RC; ++it) {
        float pe = __expf(p[it] - m);             // empty slots -> 0
        p[it] = pe;
        den += pe;
    }
    for (int e = e0 + RC * 4; e < end; e += 4)
        den += __expf(lrelu(s1[adj[e] * 8 + h] + sd) - m);
    den += __shfl_xor(den, 8);
    den += __shfl_xor(den, 16);
    float inv = 1.f / (den + 1e-16f);

    // aggregate: lane accumulates channels h*8..h*8+7 of its node
    float a[8] = {0,0,0,0,0,0,0,0};
    #pragma unroll
    for (int it = 0; it < PF; ++it) fma8raw(raw[it], p[it] * inv, a);
    #pragma unroll
    for (int it = PF; it < RC; ++it) {
        int e = e0 + it * 4;
        if (e < end) fma8h(h1 + (size_t)sv[it] * 64 + h * 8, p[it] * inv, a);
    }
    for (int e = e0 + RC * 4; e < end; e += 4) {
        int s = adj[e];
        float alpha = __expf(lrelu(s1[s * 8 + h] + sd) - m) * inv;
        fma8h(h1 + (size_t)s * 64 + h * 8, alpha, a);
    }
    #pragma unroll
    for (int j = 0; j < 8; ++j) {
        a[j] += __shfl_xor(a[j], 8);
        a[j] += __shfl_xor(a[j], 16);
    }

    // redistribute: this lane needs ch0 = tt and ch1 = tt+32
    float ha0 = 0.f, ha1 = 0.f;
    int srcA = hb + (tt >> 3);
    #pragma unroll
    for (int j = 0; j < 8; ++j) {
        float vA = __shfl(a[j], srcA);
        float vB = __shfl(a[j], srcA + 4);
        if ((tt & 7) == j) { ha0 = vA; ha1 = vB; }
    }

    // bias + ELU
    ha0 += b1[tt];
    ha1 += b1[tt + 32];
    ha0 = ha0 > 0.f ? ha0 : (__expf(ha0) - 1.f);
    ha1 = ha1 > 0.f ? ha1 : (__expf(ha1) - 1.f);

    // fused lin2
    float c0 = 0.f, c1 = 0.f;
    #pragma unroll 8
    for (int k = 0; k < 32; ++k) {
        float w = __shfl(ha0, hb + k);
        c0 += w * W2[k * 64 + tt];
        c1 += w * W2[k * 64 + tt + 32];
    }
    #pragma unroll 8
    for (int k = 0; k < 32; ++k) {
        float w = __shfl(ha1, hb + k);
        c0 += w * W2[(k + 32) * 64 + tt];
        c1 += w * W2[(k + 32) * 64 + tt + 32];
    }
    h2[n * 64 + tt]      = __float2half(c0);
    h2[n * 64 + tt + 32] = __float2half(c1);

    // layer-2 scores (reduce within 32-lane half)
    float rs = c0 * as2[tt] + c1 * as2[tt + 32];
    float rd = c0 * ad2[tt] + c1 * ad2[tt + 32];
    #pragma unroll
    for (int mk = 16; mk >= 1; mk >>= 1) {
        rs += __shfl_xor(rs, mk);
        rd += __shfl_xor(rd, mk);
    }
    if (tt == 0) { s2[n] = rs; t2[n] = rd; }
}

// ---------------- layer-2 node kernel: 2 nodes per wave ----------------

__global__ __launch_bounds__(256) void l2_kernel(
    const int* __restrict__ row, const int* __restrict__ adj,
    const __half* __restrict__ h2, const float* __restrict__ s2, const float* __restrict__ t2,
    const float* __restrict__ b2, float* __restrict__ out)
{
    int wid = threadIdx.x >> 6, t = threadIdx.x & 63;
    int half = t >> 5, tt = t & 31;
    int n = blockIdx.x * 8 + wid * 2 + half;
    int beg = row[n], end = row[n + 1];
    int slot = tt >> 3, g = tt & 7;
    float sd = t2[n];
    const int e0 = beg + slot;

    int   sv[RC];
    float p[RC];
    uint4 raw[PF];
    float m = -3e38f;
    #pragma unroll
    for (int it = 0; it < RC; ++it) {
        int e = e0 + it * 4;
        bool ok = e < end;
        int s = ok ? adj[e] : n;
        sv[it] = s;
        float v = ok ? lrelu(s2[s] + sd) : -3e38f;
        p[it] = v;
        m = fmaxf(m, v);
        if (it < PF) raw[it] = *reinterpret_cast<const uint4*>(h2 + (size_t)s * 64 + g * 8);
    }
    for (int e = e0 + RC * 4; e < end; e += 4)
        m = fmaxf(m, lrelu(s2[adj[e]] + sd));
    m = fmaxf(m, __shfl_xor(m, 8));
    m = fmaxf(m, __shfl_xor(m, 16));

    float den = 0.f;
    #pragma unroll
    for (int it = 0; it < RC; ++it) {
        float pe = __expf(p[it] - m);
        p[it] = pe;
        den += pe;
    }
    for (int e = e0 + RC * 4; e < end; e += 4)
        den += __expf(lrelu(s2[adj[e]] + sd) - m);
    den += __shfl_xor(den, 8);
    den += __shfl_xor(den, 16);
    float inv = 1.f / (den + 1e-16f);

    float a[8] = {0,0,0,0,0,0,0,0};
    #pragma unroll
    for (int it = 0; it < PF; ++it) fma8raw(raw[it], p[it] * inv, a);
    #pragma unroll
    for (int it = PF; it < RC; ++it) {
        int e = e0 + it * 4;
        if (e < end) fma8h(h2 + (size_t)sv[it] * 64 + g * 8, p[it] * inv, a);
    }
    for (int e = e0 + RC * 4; e < end; e += 4) {
        int s = adj[e];
        float alpha = __expf(lrelu(s2[s] + sd) - m) * inv;
        fma8h(h2 + (size_t)s * 64 + g * 8, alpha, a);
    }
    #pragma unroll
    for (int j = 0; j < 8; ++j) {
        a[j] += __shfl_xor(a[j], 8);
        a[j] += __shfl_xor(a[j], 16);
    }
    if (slot == 0) {
        float4 o0 = make_float4(a[0] + b2[g * 8 + 0], a[1] + b2[g * 8 + 1],
                                a[2] + b2[g * 8 + 2], a[3] + b2[g * 8 + 3]);
        float4 o1 = make_float4(a[4] + b2[g * 8 + 4], a[5] + b2[g * 8 + 5],
                                a[6] + b2[g * 8 + 6], a[7] + b2[g * 8 + 7]);
        float4* op = (float4*)(out + (size_t)n * 64 + g * 8);
        op[0] = o0; op[1] = o1;
    }
}

extern "C" void kernel_launch(void* const* d_in, const int* in_sizes, int n_in,
                              void* d_out, int out_size, void* d_ws, size_t ws_size,
                              hipStream_t stream)
{
    const float* x   = (const float*)d_in[0];
    const int* ei    = (const int*)d_in[1];
    const float* W1  = (const float*)d_in[2];
    const float* as1 = (const float*)d_in[3];
    const float* ad1 = (const float*)d_in[4];
    const float* b1  = (const float*)d_in[5];
    const float* W2  = (const float*)d_in[6];
    const float* as2 = (const float*)d_in[7];
    const float* ad2 = (const float*)d_in[8];
    const float* b2  = (const float*)d_in[9];
    float* out = (float*)d_out;

    char* wsb = (char*)d_ws;
    __half* h1  = (__half*)wsb;                       // N*64 fp16
    __half* h2  = h1 + (size_t)N_NODES * 64;          // N*64 fp16
    float*  s1  = (float*)(h2 + (size_t)N_NODES * 64);// N*8
    float*  t1  = s1 + N_NODES * 8;                   // N*8
    float*  s2  = t1 + N_NODES * 8;                   // N
    float*  t2  = s2 + N_NODES;                       // N
    int*    cnt8 = (int*)(t2 + N_NODES);              // 8*N
    int*    off8 = cnt8 + 8 * N_NODES;                // 8*N
    int*    rowp = off8 + 8 * N_NODES;                // N+1
    int*    aux  = rowp + N_NODES + 1;                // NTILES
    int*    adj  = aux + NTILES;                      // ET
    int*    pos  = adj + ET;                          // ET

    hipMemsetAsync(cnt8, 0, 8 * N_NODES * sizeof(int), stream);

    cl1_kernel<<<EB + LIN1_BLOCKS, 256, 0, stream>>>(ei, cnt8, pos, x, W1, as1, ad1, h1, s1, t1);

    scanA_kernel<<<NTILES, SCAN_TILE, 0, stream>>>(cnt8, rowp, aux);
    scanB_kernel<<<1, SCAN_TILE, 0, stream>>>(aux, rowp);
    scanC_kernel<<<NTILES, SCAN_TILE, 0, stream>>>(aux, rowp, cnt8, off8);
    fill_kernel<<<EB, 256, 0, stream>>>(ei, off8, pos, adj);

    l1_kernel<<<N_NODES / 8, 256, 0, stream>>>(rowp, adj, h1, s1, t1,
                                               b1, W2, as2, ad2, h2, s2, t2);

    l2_kernel<<<N_NODES / 8, 256, 0, stream>>>(rowp, adj, h2, s2, t2, b2, out);
}

// Round 14
// 230.166 us; speedup vs baseline: 1.0812x; 1.0812x over previous
//
#include <hip/hip_runtime.h>
#include <hip/hip_fp16.h>
#include <math.h>

#define N_NODES 50000
#define N_EDGES 800000
#define ET (N_EDGES + N_NODES)   // edges + self loops
#define IN_DIM 128
#define H1DIM 64                 // HEADS*HID
#define HEADS 8
#define HID 8
#define OUT_DIM 64
#define NEG_SLOPE 0.2f

#define SCAN_TILE 256
#define NTILES ((N_NODES + SCAN_TILE - 1) / SCAN_TILE)   // 196
#define RC 8                      // cached score iterations per lane (4 slots -> deg <= 32)
#define PF 6                      // prefetched feature-row iterations (deg <= 24)

#define LIN1_WAVES (N_NODES / 8)                 // 6250
#define LIN1_BLOCKS ((LIN1_WAVES + 3) / 4)       // 1563
#define EB ((ET + 255) / 256)                    // 3321

__device__ __forceinline__ float lrelu(float v) { return v >= 0.f ? v : NEG_SLOPE * v; }

__device__ __forceinline__ float rdlane(float v, int l) {
    return __int_as_float(__builtin_amdgcn_readlane(__float_as_int(v), l));
}

// real XCD id (gfx950; measured learn_hip m09). Wave-uniform.
__device__ __forceinline__ int xcc_id() {
    int v;
    asm volatile("s_getreg_b32 %0, hwreg(HW_REG_XCC_ID)" : "=s"(v));
    return v & 7;
}

// unpack 8 fp16 (raw uint4) and FMA into a[8]
__device__ __forceinline__ void fma8raw(uint4 u, float alpha, float* a) {
    float2 f0 = __half22float2(*(const __half2*)&u.x);
    float2 f1 = __half22float2(*(const __half2*)&u.y);
    float2 f2 = __half22float2(*(const __half2*)&u.z);
    float2 f3 = __half22float2(*(const __half2*)&u.w);
    a[0] += f0.x * alpha; a[1] += f0.y * alpha;
    a[2] += f1.x * alpha; a[3] += f1.y * alpha;
    a[4] += f2.x * alpha; a[5] += f2.y * alpha;
    a[6] += f3.x * alpha; a[7] += f3.y * alpha;
}

__device__ __forceinline__ void fma8h(const __half* __restrict__ base, float alpha, float* a) {
    fma8raw(*reinterpret_cast<const uint4*>(base), alpha, a);
}

// edge_index is int32 on device (validated round 4)
__device__ __forceinline__ void edge_nodes(const int* __restrict__ ei, int e, int& s, int& d) {
    if (e < N_EDGES) { s = ei[e]; d = ei[N_EDGES + e]; }
    else             { s = e - N_EDGES; d = s; }
}

// ---------------- fused: lin1 (blocks [0,LIN1_BLOCKS)) + count-with-pos (rest) ----------------
// counters privatized by REAL XCD id -> copy c's cache lines only ever touched by XCD c.

__global__ __launch_bounds__(256) void cl1_kernel(
    const int* __restrict__ ei, int* __restrict__ cnt8, int* __restrict__ pos,
    const float* __restrict__ x, const float* __restrict__ W1,
    const float* __restrict__ a_src, const float* __restrict__ a_dst,
    __half* __restrict__ h1, float* __restrict__ ssrc, float* __restrict__ sdst)
{
    if (blockIdx.x >= LIN1_BLOCKS) {
        int i = (blockIdx.x - LIN1_BLOCKS) * 256 + threadIdx.x;
        if (i >= ET) return;
        int s, d; edge_nodes(ei, i, s, d);
        int c = xcc_id();
        int r = atomicAdd(&cnt8[c * N_NODES + d], 1);
        pos[i] = r | (c << 28);              // store copy id with the rank
        return;
    }
    int wid = threadIdx.x >> 6, t = threadIdx.x & 63;
    int g = blockIdx.x * 4 + wid;
    if (g >= LIN1_WAVES) return;
    int n0 = g * 8;

    float x0[8], x1[8];
    #pragma unroll
    for (int nn = 0; nn < 8; ++nn) {
        x0[nn] = x[(n0 + nn) * IN_DIM + t];
        x1[nn] = x[(n0 + nn) * IN_DIM + 64 + t];
    }
    float acc[8] = {0,0,0,0,0,0,0,0};
    #pragma unroll 8
    for (int k = 0; k < 64; ++k) {
        float w = W1[k * 64 + t];
        #pragma unroll
        for (int nn = 0; nn < 8; ++nn) acc[nn] += rdlane(x0[nn], k) * w;
    }
    #pragma unroll 8
    for (int k = 0; k < 64; ++k) {
        float w = W1[(k + 64) * 64 + t];
        #pragma unroll
        for (int nn = 0; nn < 8; ++nn) acc[nn] += rdlane(x1[nn], k) * w;
    }

    float av = a_src[t], bv = a_dst[t];
    #pragma unroll
    for (int nn = 0; nn < 8; ++nn) {
        int n = n0 + nn;
        h1[n * 64 + t] = __float2half(acc[nn]);
        float rs = acc[nn] * av, rd = acc[nn] * bv;
        rs += __shfl_xor(rs, 1); rs += __shfl_xor(rs, 2); rs += __shfl_xor(rs, 4);
        rd += __shfl_xor(rd, 1); rd += __shfl_xor(rd, 2); rd += __shfl_xor(rd, 4);
        if ((t & 7) == 0) { ssrc[n * 8 + (t >> 3)] = rs; sdst[n * 8 + (t >> 3)] = rd; }
    }
}

// ---------------- scans ----------------

__global__ __launch_bounds__(SCAN_TILE) void scanA_kernel(
    const int* __restrict__ cnt8, int* __restrict__ row, int* __restrict__ aux)
{
    __shared__ int sh[SCAN_TILE];
    int t = threadIdx.x, i = blockIdx.x * SCAN_TILE + t;
    int v = 0;
    if (i < N_NODES) {
        #pragma unroll
        for (int c = 0; c < 8; ++c) v += cnt8[c * N_NODES + i];
    }
    sh[t] = v;
    __syncthreads();
    #pragma unroll
    for (int off = 1; off < SCAN_TILE; off <<= 1) {
        int add = (t >= off) ? sh[t - off] : 0;
        __syncthreads();
        sh[t] += add;
        __syncthreads();
    }
    if (i < N_NODES) row[i] = sh[t] - v;
    if (t == SCAN_TILE - 1) aux[blockIdx.x] = sh[t];
}

__global__ __launch_bounds__(SCAN_TILE) void scanB_kernel(int* __restrict__ aux, int* __restrict__ row) {
    __shared__ int sh[SCAN_TILE];
    int t = threadIdx.x;
    int v = (t < NTILES) ? aux[t] : 0;
    sh[t] = v;
    __syncthreads();
    #pragma unroll
    for (int off = 1; off < SCAN_TILE; off <<= 1) {
        int add = (t >= off) ? sh[t - off] : 0;
        __syncthreads();
        sh[t] += add;
        __syncthreads();
    }
    if (t < NTILES) aux[t] = sh[t] - v;
    if (t == NTILES - 1) row[N_NODES] = sh[t];
}

// finalize row and emit per-copy base offsets
__global__ __launch_bounds__(SCAN_TILE) void scanC_kernel(
    const int* __restrict__ aux, int* __restrict__ row,
    const int* __restrict__ cnt8, int* __restrict__ off8)
{
    int i = blockIdx.x * SCAN_TILE + threadIdx.x;
    if (i >= N_NODES) return;
    int r = row[i] + aux[i >> 8];
    row[i] = r;
    int run = r;
    #pragma unroll
    for (int c = 0; c < 8; ++c) {
        off8[c * N_NODES + i] = run;
        run += cnt8[c * N_NODES + i];
    }
}

// atomic-free fill: copy id recovered from pos high bits
__global__ void fill_kernel(const int* __restrict__ ei, const int* __restrict__ off8,
                            const int* __restrict__ pos, int* __restrict__ adj)
{
    int i = blockIdx.x * blockDim.x + threadIdx.x;
    if (i >= ET) return;
    int s, d; edge_nodes(ei, i, s, d);
    int pr = pos[i];
    int c = (unsigned)pr >> 28;
    int r = pr & 0x0FFFFFFF;
    adj[off8[c * N_NODES + d] + r] = s;
}

// ---------------- layer-1 node kernel: 2 nodes per wave ----------------
// lane t: half = t>>5 (node select), tt = t&31, slot = tt>>3 (4 slots), h = tt&7

__global__ __launch_bounds__(256) void l1_kernel(
    const int* __restrict__ row, const int* __restrict__ adj,
    const __half* __restrict__ h1, const float* __restrict__ s1, const float* __restrict__ t1,
    const float* __restrict__ b1, const float* __restrict__ W2,
    const float* __restrict__ as2, const float* __restrict__ ad2,
    __half* __restrict__ h2, float* __restrict__ s2, float* __restrict__ t2)
{
    int wid = threadIdx.x >> 6, t = threadIdx.x & 63;
    int half = t >> 5, tt = t & 31;
    int n = blockIdx.x * 8 + wid * 2 + half;
    int beg = row[n], end = row[n + 1];
    int slot = tt >> 3, h = tt & 7;
    float sd = t1[n * 8 + h];
    const int e0 = beg + slot;
    const int hb = half << 5;                     // half base lane

    // pass 1: gather scores + prefetch first PF feature rows
    int   sv[RC];
    float p[RC];
    uint4 raw[PF];
    float m = -3e38f;
    #pragma unroll
    for (int it = 0; it < RC; ++it) {
        int e = e0 + it * 4;
        bool ok = e < end;
        int s = ok ? adj[e] : n;
        sv[it] = s;
        float v = ok ? lrelu(s1[s * 8 + h] + sd) : -3e38f;
        p[it] = v;
        m = fmaxf(m, v);
        if (it < PF) raw[it] = *reinterpret_cast<const uint4*>(h1 + (size_t)s * 64 + h * 8);
    }
    for (int e = e0 + RC * 4; e < end; e += 4)    // improbable tail (deg > 32)
        m = fmaxf(m, lrelu(s1[adj[e] * 8 + h] + sd));
    m = fmaxf(m, __shfl_xor(m, 8));
    m = fmaxf(m, __shfl_xor(m, 16));

    float den = 0.f;
    #pragma unroll
    for (int it = 0; it < RC; ++it) {
        float pe = __expf(p[it] - m);             // empty slots -> 0
        p[it] = pe;
        den += pe;
    }
    for (int e = e0 + RC * 4; e < end; e += 4)
        den += __expf(lrelu(s1[adj[e] * 8 + h] + sd) - m);
    den += __shfl_xor(den, 8);
    den += __shfl_xor(den, 16);
    float inv = 1.f / (den + 1e-16f);

    // aggregate: lane accumulates channels h*8..h*8+7 of its node
    float a[8] = {0,0,0,0,0,0,0,0};
    #pragma unroll
    for (int it = 0; it < PF; ++it) fma8raw(raw[it], p[it] * inv, a);
    #pragma unroll
    for (int it = PF; it < RC; ++it) {
        int e = e0 + it * 4;
        if (e < end) fma8h(h1 + (size_t)sv[it] * 64 + h * 8, p[it] * inv, a);
    }
    for (int e = e0 + RC * 4; e < end; e += 4) {
        int s = adj[e];
        float alpha = __expf(lrelu(s1[s * 8 + h] + sd) - m) * inv;
        fma8h(h1 + (size_t)s * 64 + h * 8, alpha, a);
    }
    #pragma unroll
    for (int j = 0; j < 8; ++j) {
        a[j] += __shfl_xor(a[j], 8);
        a[j] += __shfl_xor(a[j], 16);
    }

    // redistribute: this lane needs ch0 = tt and ch1 = tt+32
    float ha0 = 0.f, ha1 = 0.f;
    int srcA = hb + (tt >> 3);
    #pragma unroll
    for (int j = 0; j < 8; ++j) {
        float vA = __shfl(a[j], srcA);
        float vB = __shfl(a[j], srcA + 4);
        if ((tt & 7) == j) { ha0 = vA; ha1 = vB; }
    }

    // bias + ELU
    ha0 += b1[tt];
    ha1 += b1[tt + 32];
    ha0 = ha0 > 0.f ? ha0 : (__expf(ha0) - 1.f);
    ha1 = ha1 > 0.f ? ha1 : (__expf(ha1) - 1.f);

    // fused lin2
    float c0 = 0.f, c1 = 0.f;
    #pragma unroll 8
    for (int k = 0; k < 32; ++k) {
        float w = __shfl(ha0, hb + k);
        c0 += w * W2[k * 64 + tt];
        c1 += w * W2[k * 64 + tt + 32];
    }
    #pragma unroll 8
    for (int k = 0; k < 32; ++k) {
        float w = __shfl(ha1, hb + k);
        c0 += w * W2[(k + 32) * 64 + tt];
        c1 += w * W2[(k + 32) * 64 + tt + 32];
    }
    h2[n * 64 + tt]      = __float2half(c0);
    h2[n * 64 + tt + 32] = __float2half(c1);

    // layer-2 scores (reduce within 32-lane half)
    float rs = c0 * as2[tt] + c1 * as2[tt + 32];
    float rd = c0 * ad2[tt] + c1 * ad2[tt + 32];
    #pragma unroll
    for (int mk = 16; mk >= 1; mk >>= 1) {
        rs += __shfl_xor(rs, mk);
        rd += __shfl_xor(rd, mk);
    }
    if (tt == 0) { s2[n] = rs; t2[n] = rd; }
}

// ---------------- layer-2 node kernel: 2 nodes per wave ----------------

__global__ __launch_bounds__(256) void l2_kernel(
    const int* __restrict__ row, const int* __restrict__ adj,
    const __half* __restrict__ h2, const float* __restrict__ s2, const float* __restrict__ t2,
    const float* __restrict__ b2, float* __restrict__ out)
{
    int wid = threadIdx.x >> 6, t = threadIdx.x & 63;
    int half = t >> 5, tt = t & 31;
    int n = blockIdx.x * 8 + wid * 2 + half;
    int beg = row[n], end = row[n + 1];
    int slot = tt >> 3, g = tt & 7;
    float sd = t2[n];
    const int e0 = beg + slot;

    int   sv[RC];
    float p[RC];
    uint4 raw[PF];
    float m = -3e38f;
    #pragma unroll
    for (int it = 0; it < RC; ++it) {
        int e = e0 + it * 4;
        bool ok = e < end;
        int s = ok ? adj[e] : n;
        sv[it] = s;
        float v = ok ? lrelu(s2[s] + sd) : -3e38f;
        p[it] = v;
        m = fmaxf(m, v);
        if (it < PF) raw[it] = *reinterpret_cast<const uint4*>(h2 + (size_t)s * 64 + g * 8);
    }
    for (int e = e0 + RC * 4; e < end; e += 4)
        m = fmaxf(m, lrelu(s2[adj[e]] + sd));
    m = fmaxf(m, __shfl_xor(m, 8));
    m = fmaxf(m, __shfl_xor(m, 16));

    float den = 0.f;
    #pragma unroll
    for (int it = 0; it < RC; ++it) {
        float pe = __expf(p[it] - m);
        p[it] = pe;
        den += pe;
    }
    for (int e = e0 + RC * 4; e < end; e += 4)
        den += __expf(lrelu(s2[adj[e]] + sd) - m);
    den += __shfl_xor(den, 8);
    den += __shfl_xor(den, 16);
    float inv = 1.f / (den + 1e-16f);

    float a[8] = {0,0,0,0,0,0,0,0};
    #pragma unroll
    for (int it = 0; it < PF; ++it) fma8raw(raw[it], p[it] * inv, a);
    #pragma unroll
    for (int it = PF; it < RC; ++it) {
        int e = e0 + it * 4;
        if (e < end) fma8h(h2 + (size_t)sv[it] * 64 + g * 8, p[it] * inv, a);
    }
    for (int e = e0 + RC * 4; e < end; e += 4) {
        int s = adj[e];
        float alpha = __expf(lrelu(s2[s] + sd) - m) * inv;
        fma8h(h2 + (size_t)s * 64 + g * 8, alpha, a);
    }
    #pragma unroll
    for (int j = 0; j < 8; ++j) {
        a[j] += __shfl_xor(a[j], 8);
        a[j] += __shfl_xor(a[j], 16);
    }
    if (slot == 0) {
        float4 o0 = make_float4(a[0] + b2[g * 8 + 0], a[1] + b2[g * 8 + 1],
                                a[2] + b2[g * 8 + 2], a[3] + b2[g * 8 + 3]);
        float4 o1 = make_float4(a[4] + b2[g * 8 + 4], a[5] + b2[g * 8 + 5],
                                a[6] + b2[g * 8 + 6], a[7] + b2[g * 8 + 7]);
        float4* op = (float4*)(out + (size_t)n * 64 + g * 8);
        op[0] = o0; op[1] = o1;
    }
}

extern "C" void kernel_launch(void* const* d_in, const int* in_sizes, int n_in,
                              void* d_out, int out_size, void* d_ws, size_t ws_size,
                              hipStream_t stream)
{
    const float* x   = (const float*)d_in[0];
    const int* ei    = (const int*)d_in[1];
    const float* W1  = (const float*)d_in[2];
    const float* as1 = (const float*)d_in[3];
    const float* ad1 = (const float*)d_in[4];
    const float* b1  = (const float*)d_in[5];
    const float* W2  = (const float*)d_in[6];
    const float* as2 = (const float*)d_in[7];
    const float* ad2 = (const float*)d_in[8];
    const float* b2  = (const float*)d_in[9];
    float* out = (float*)d_out;

    char* wsb = (char*)d_ws;
    __half* h1  = (__half*)wsb;                       // N*64 fp16
    __half* h2  = h1 + (size_t)N_NODES * 64;          // N*64 fp16
    float*  s1  = (float*)(h2 + (size_t)N_NODES * 64);// N*8
    float*  t1  = s1 + N_NODES * 8;                   // N*8
    float*  s2  = t1 + N_NODES * 8;                   // N
    float*  t2  = s2 + N_NODES;                       // N
    int*    cnt8 = (int*)(t2 + N_NODES);              // 8*N
    int*    off8 = cnt8 + 8 * N_NODES;                // 8*N
    int*    rowp = off8 + 8 * N_NODES;                // N+1
    int*    aux  = rowp + N_NODES + 1;                // NTILES
    int*    adj  = aux + NTILES;                      // ET
    int*    pos  = adj + ET;                          // ET

    hipMemsetAsync(cnt8, 0, 8 * N_NODES * sizeof(int), stream);

    cl1_kernel<<<LIN1_BLOCKS + EB, 256, 0, stream>>>(ei, cnt8, pos, x, W1, as1, ad1, h1, s1, t1);

    scanA_kernel<<<NTILES, SCAN_TILE, 0, stream>>>(cnt8, rowp, aux);
    scanB_kernel<<<1, SCAN_TILE, 0, stream>>>(aux, rowp);
    scanC_kernel<<<NTILES, SCAN_TILE, 0, stream>>>(aux, rowp, cnt8, off8);
    fill_kernel<<<EB, 256, 0, stream>>>(ei, off8, pos, adj);

    l1_kernel<<<N_NODES / 8, 256, 0, stream>>>(rowp, adj, h1, s1, t1,
                                               b1, W2, as2, ad2, h2, s2, t2);

    l2_kernel<<<N_NODES / 8, 256, 0, stream>>>(rowp, adj, h2, s2, t2, b2, out);
}